// Round 1
// baseline (925.831 us; speedup 1.0000x reference)
//
#include <hip/hip_runtime.h>
#include <hip/hip_bf16.h>
#include <cstdint>

typedef _Float16 f16;
typedef _Float16 half8 __attribute__((ext_vector_type(8)));
typedef float f32x4 __attribute__((ext_vector_type(4)));

#define SCALE 0.125f

// ---------------- prep: x (64,256,1024) f32 -> xT (64,1024,256) f16 ----------------
__global__ __launch_bounds__(256) void prep_xT(const float* __restrict__ x, f16* __restrict__ xT) {
  __shared__ float tile[32][33];
  int b = blockIdx.z, nt = blockIdx.y, dt = blockIdx.x;
  int c = threadIdx.x & 31, rp = threadIdx.x >> 5;
  const float* xb = x + ((size_t)b*256 + nt*32)*1024 + dt*32;
#pragma unroll
  for (int p = 0; p < 4; ++p) { int r = p*8 + rp; tile[r][c] = xb[(size_t)r*1024 + c]; }
  __syncthreads();
  f16* o = xT + ((size_t)b*1024 + dt*32)*256 + nt*32;
#pragma unroll
  for (int p = 0; p < 4; ++p) { int r = p*8 + rp; o[(size_t)r*256 + c] = (f16)tile[c][r]; }
}

// ---------------- prep: Wkv (1024,1024) f32 -> WkvT (1024,1024) f16 (WkvT[n][k]=Wkv[k][n]) ----
__global__ __launch_bounds__(256) void prep_WkvT(const float* __restrict__ W, f16* __restrict__ Wt) {
  __shared__ float tile[32][33];
  int kt = blockIdx.x, nt = blockIdx.y;
  int c = threadIdx.x & 31, rp = threadIdx.x >> 5;
#pragma unroll
  for (int p = 0; p < 4; ++p) { int r = p*8+rp; tile[r][c] = W[(size_t)(kt*32 + r)*1024 + nt*32 + c]; }
  __syncthreads();
#pragma unroll
  for (int p = 0; p < 4; ++p) { int r = p*8+rp; Wt[(size_t)(nt*32 + r)*1024 + kt*32 + c] = (f16)tile[c][r]; }
}

// ---------------- prep: Wspec (256,768) f32 -> WspecT (512,256) f16 (first 512 cols, transposed) ----
__global__ __launch_bounds__(256) void prep_WspecT(const float* __restrict__ W, f16* __restrict__ Wt) {
  __shared__ float tile[32][33];
  int jt = blockIdx.x, ct = blockIdx.y;
  int c = threadIdx.x & 31, rp = threadIdx.x >> 5;
#pragma unroll
  for (int p = 0; p < 4; ++p) { int r = p*8+rp; tile[r][c] = W[(size_t)(ct*32 + r)*768 + jt*32 + c]; }
  __syncthreads();
#pragma unroll
  for (int p = 0; p < 4; ++p) { int r = p*8+rp; Wt[(size_t)(jt*32 + r)*256 + ct*32 + c] = (f16)tile[c][r]; }
}

// ---------------- kv GEMM: (16384,1024) f32 x @ WkvT -> kv f16 (16384,1024) ----------------
__global__ __launch_bounds__(256) void gemm_kv(const float* __restrict__ x, const f16* __restrict__ WkvT,
                                               f16* __restrict__ kv) {
  int lane = threadIdx.x & 63, wave = threadIdx.x >> 6;
  int l15 = lane & 15, l4 = lane >> 4;
  int wm = wave & 1, wn = wave >> 1;
  size_t m0 = (size_t)blockIdx.x*128 + wm*64;
  size_t n0 = (size_t)blockIdx.y*128 + wn*64;
  const float* Ap = x + (m0 + l15)*1024 + 8*l4;
  const f16*   Bp = WkvT + (n0 + l15)*1024 + 8*l4;
  f32x4 acc[4][4];
#pragma unroll
  for (int i=0;i<4;++i)
#pragma unroll
    for (int j=0;j<4;++j) acc[i][j] = (f32x4){0.f,0.f,0.f,0.f};
  for (int k0 = 0; k0 < 1024; k0 += 32) {
    half8 a[4], bb[4];
#pragma unroll
    for (int i=0;i<4;++i) {
      const float* p = Ap + (size_t)i*16*1024 + k0;
      f32x4 lo = *(const f32x4*)p;
      f32x4 hi = *(const f32x4*)(p+4);
      half8 h;
      h[0]=(f16)lo[0]; h[1]=(f16)lo[1]; h[2]=(f16)lo[2]; h[3]=(f16)lo[3];
      h[4]=(f16)hi[0]; h[5]=(f16)hi[1]; h[6]=(f16)hi[2]; h[7]=(f16)hi[3];
      a[i]=h;
    }
#pragma unroll
    for (int i=0;i<4;++i) bb[i] = *(const half8*)(Bp + (size_t)i*16*1024 + k0);
#pragma unroll
    for (int mi=0;mi<4;++mi)
#pragma unroll
      for (int ni=0;ni<4;++ni)
        acc[mi][ni] = __builtin_amdgcn_mfma_f32_16x16x32_f16(a[mi], bb[ni], acc[mi][ni], 0,0,0);
  }
#pragma unroll
  for (int mi=0;mi<4;++mi)
#pragma unroll
    for (int ni=0;ni<4;++ni)
#pragma unroll
      for (int j=0;j<4;++j) {
        size_t row = m0 + mi*16 + 4*l4 + j;
        size_t col = n0 + ni*16 + l15;
        kv[row*1024 + col] = (f16)acc[mi][ni][j];
      }
}

// ---------------- qs GEMM: per b: xT[b] (1024,256) @ WspecT^T -> qks[b] (1024,512) f16 ----------
__global__ __launch_bounds__(256) void gemm_qs(const f16* __restrict__ xT, const f16* __restrict__ WspecT,
                                               f16* __restrict__ qks) {
  int b = blockIdx.z;
  const f16* A = xT + (size_t)b*1024*256;
  f16* C = qks + (size_t)b*1024*512;
  int lane = threadIdx.x & 63, wave = threadIdx.x >> 6;
  int l15 = lane & 15, l4 = lane >> 4;
  int wm = wave & 1, wn = wave >> 1;
  size_t m0 = (size_t)blockIdx.x*128 + wm*64;
  size_t n0 = (size_t)blockIdx.y*128 + wn*64;
  const f16* Ap = A + (m0 + l15)*256 + 8*l4;
  const f16* Bp = WspecT + (n0 + l15)*256 + 8*l4;
  f32x4 acc[4][4];
#pragma unroll
  for (int i=0;i<4;++i)
#pragma unroll
    for (int j=0;j<4;++j) acc[i][j] = (f32x4){0.f,0.f,0.f,0.f};
  for (int k0 = 0; k0 < 256; k0 += 32) {
    half8 a[4], bb[4];
#pragma unroll
    for (int i=0;i<4;++i) a[i]  = *(const half8*)(Ap + (size_t)i*16*256 + k0);
#pragma unroll
    for (int i=0;i<4;++i) bb[i] = *(const half8*)(Bp + (size_t)i*16*256 + k0);
#pragma unroll
    for (int mi=0;mi<4;++mi)
#pragma unroll
      for (int ni=0;ni<4;++ni)
        acc[mi][ni] = __builtin_amdgcn_mfma_f32_16x16x32_f16(a[mi], bb[ni], acc[mi][ni], 0,0,0);
  }
#pragma unroll
  for (int mi=0;mi<4;++mi)
#pragma unroll
    for (int ni=0;ni<4;++ni)
#pragma unroll
      for (int j=0;j<4;++j) {
        size_t row = m0 + mi*16 + 4*l4 + j;
        size_t col = n0 + ni*16 + l15;
        C[row*512 + col] = (f16)acc[mi][ni][j];
      }
}

// ---------------- qattn: per (b,h): q = x_center @ Wq, attn over 256, out -> attnout (64,512) f32 ----
__global__ __launch_bounds__(256) void qattn(const float* __restrict__ x, const float* __restrict__ Wq,
                                             const f16* __restrict__ kv, float* __restrict__ attnout) {
  int b = blockIdx.x, h = blockIdx.y;
  int t = threadIdx.x;
  __shared__ float xc[1024];
  __shared__ float qh[64];
  __shared__ float p[256];
  __shared__ float part[4][64];
  __shared__ float redw[4];
  const float* xcg = x + ((size_t)b*256 + 128)*1024;
#pragma unroll
  for (int i = 0; i < 4; ++i) xc[t + 256*i] = xcg[t + 256*i];
  __syncthreads();
  int d = t & 63, chunk = t >> 6;
  {
    float s = 0.f;
    const float* wq = Wq + (size_t)(chunk*256)*512 + h*64 + d;
    for (int c = 0; c < 256; ++c) s += xc[chunk*256 + c] * wq[(size_t)c*512];
    part[chunk][d] = s;
  }
  __syncthreads();
  if (t < 64) qh[t] = part[0][t]+part[1][t]+part[2][t]+part[3][t];
  __syncthreads();
  {
    const f16* kp = kv + ((size_t)b*256 + t)*1024 + h*64;
    float acc = 0.f;
#pragma unroll
    for (int d8 = 0; d8 < 8; ++d8) {
      half8 kk = *(const half8*)(kp + d8*8);
#pragma unroll
      for (int j = 0; j < 8; ++j) acc += (float)kk[j] * qh[d8*8+j];
    }
    p[t] = acc * SCALE;
  }
  __syncthreads();
  int lane = t & 63, wid = t >> 6;
  float v = p[t];
#pragma unroll
  for (int o = 32; o >= 1; o >>= 1) v = fmaxf(v, __shfl_xor(v, o));
  if (lane == 0) redw[wid] = v;
  __syncthreads();
  float m = fmaxf(fmaxf(redw[0],redw[1]),fmaxf(redw[2],redw[3]));
  float e = __expf(p[t] - m);
  __syncthreads();
  v = e;
#pragma unroll
  for (int o = 32; o >= 1; o >>= 1) v += __shfl_xor(v, o);
  if (lane == 0) redw[wid] = v;
  __syncthreads();
  float Z = redw[0]+redw[1]+redw[2]+redw[3];
  p[t] = e / Z;
  __syncthreads();
  {
    float o = 0.f;
    const f16* vp = kv + ((size_t)b*256 + chunk*64)*1024 + 512 + h*64 + d;
    for (int n = 0; n < 64; ++n) o += p[chunk*64 + n] * (float)vp[(size_t)n*1024];
    part[chunk][d] = o;
  }
  __syncthreads();
  if (t < 64) attnout[(size_t)b*512 + h*64 + t] = part[0][t]+part[1][t]+part[2][t]+part[3][t];
}

// ---------------- spatial: (64,512) @ Wout (512,1024) + bout -> spatial (64,1024) f32 ----------
__global__ __launch_bounds__(256) void spatialk(const float* __restrict__ attnout, const float* __restrict__ Wout,
                                                const float* __restrict__ bout, float* __restrict__ spatial) {
  int b = blockIdx.x, t = threadIdx.x;
  __shared__ float ao[512];
  ao[t] = attnout[(size_t)b*512 + t];
  ao[t+256] = attnout[(size_t)b*512 + 256 + t];
  __syncthreads();
#pragma unroll
  for (int rep = 0; rep < 4; ++rep) {
    int e = rep*256 + t;
    float acc = bout[e];
#pragma unroll 8
    for (int i = 0; i < 512; ++i) acc += ao[i] * Wout[(size_t)i*1024 + e];
    spatial[(size_t)b*1024 + e] = acc;
  }
}

// ---------------- spec: per (b, 32-row block): L = q_s @ k_s^T * S, row-softmax, r += spatial·w ----
__global__ __launch_bounds__(256) void speck(const f16* __restrict__ qks, const float* __restrict__ spatial,
                                             float* __restrict__ r) {
  int iblk = blockIdx.x, b = blockIdx.y;
  int tid = threadIdx.x, lane = tid & 63, wave = tid >> 6;
  int iw = wave & 1, eh = wave >> 1;
  int l15 = lane & 15, l4 = lane >> 4;
  const f16* qs = qks + (size_t)b*1024*512;
  int i0 = iblk*32 + iw*16;
  f32x4 acc[32];
#pragma unroll
  for (int t=0;t<32;++t) acc[t] = (f32x4){0.f,0.f,0.f,0.f};
  const f16* Ap = qs + (size_t)(i0 + l15)*512 + 8*l4;
  const f16* Bp = qs + 256 + (size_t)(eh*512 + l15)*512 + 8*l4;
  for (int k0 = 0; k0 < 256; k0 += 32) {
    half8 a = *(const half8*)(Ap + k0);
#pragma unroll
    for (int t = 0; t < 32; ++t) {
      half8 bb = *(const half8*)(Bp + (size_t)t*16*512 + k0);
      acc[t] = __builtin_amdgcn_mfma_f32_16x16x32_f16(a, bb, acc[t], 0,0,0);
    }
  }
  // scale by SCALE
#pragma unroll
  for (int t=0;t<32;++t)
#pragma unroll
    for (int j=0;j<4;++j) acc[t][j] *= SCALE;
  // row max over this wave's 512 cols
  float m[4] = {-1e30f,-1e30f,-1e30f,-1e30f};
#pragma unroll
  for (int t=0;t<32;++t)
#pragma unroll
    for (int j=0;j<4;++j) m[j] = fmaxf(m[j], acc[t][j]);
#pragma unroll
  for (int o = 1; o < 16; o <<= 1)
#pragma unroll
    for (int j=0;j<4;++j) m[j] = fmaxf(m[j], __shfl_xor(m[j], o));
  __shared__ float sm[2][2][16];
  __shared__ float sz[2][2][16];
  if (l15 == 0) {
#pragma unroll
    for (int j=0;j<4;++j) sm[iw][eh][4*l4+j] = m[j];
  }
  __syncthreads();
#pragma unroll
  for (int j=0;j<4;++j) m[j] = fmaxf(sm[iw][0][4*l4+j], sm[iw][1][4*l4+j]);
  // exp + row sum
  float z[4] = {0.f,0.f,0.f,0.f};
#pragma unroll
  for (int t=0;t<32;++t)
#pragma unroll
    for (int j=0;j<4;++j) { float e = __expf(acc[t][j] - m[j]); acc[t][j] = e; z[j] += e; }
#pragma unroll
  for (int o = 1; o < 16; o <<= 1)
#pragma unroll
    for (int j=0;j<4;++j) z[j] += __shfl_xor(z[j], o);
  if (l15 == 0) {
#pragma unroll
    for (int j=0;j<4;++j) sz[iw][eh][4*l4+j] = z[j];
  }
  __syncthreads();
  float f[4];
#pragma unroll
  for (int j=0;j<4;++j) {
    float zz = sz[iw][0][4*l4+j] + sz[iw][1][4*l4+j];
    f[j] = spatial[(size_t)b*1024 + i0 + 4*l4 + j] / zz;
  }
  float* rb = r + (size_t)b*1024;
#pragma unroll
  for (int t=0;t<32;++t) {
    float v = f[0]*acc[t][0] + f[1]*acc[t][1] + f[2]*acc[t][2] + f[3]*acc[t][3];
    v += __shfl_xor(v, 16);
    v += __shfl_xor(v, 32);
    if (l4 == 0) atomicAdd(rb + eh*512 + t*16 + l15, v);
  }
}

// ---------------- broadcast: out[b,n,:] = r[b,:] ----------------
__global__ __launch_bounds__(256) void bcast(const float* __restrict__ r, float* __restrict__ out) {
  size_t row = blockIdx.x;
  int b = (int)(row >> 8);
  f32x4 v = *(const f32x4*)(r + (size_t)b*1024 + threadIdx.x*4);
  *(f32x4*)(out + row*1024 + (size_t)threadIdx.x*4) = v;
}

extern "C" void kernel_launch(void* const* d_in, const int* in_sizes, int n_in,
                              void* d_out, int out_size, void* d_ws, size_t ws_size,
                              hipStream_t stream) {
  const float* x     = (const float*)d_in[0];
  const float* Wq    = (const float*)d_in[1];
  const float* Wkv   = (const float*)d_in[2];
  const float* Wout  = (const float*)d_in[3];
  const float* bout  = (const float*)d_in[4];
  const float* Wspec = (const float*)d_in[5];
  float* out = (float*)d_out;
  char* ws = (char*)d_ws;
  // workspace layout (~99 MB). kv aliases qks: kv's last read (qattn) precedes gemm_qs's write.
  f16*  qks     = (f16*)(ws);                    // 64 MB (64*1024*512*2)
  f16*  kv      = (f16*)(ws);                    // 32 MB alias, dead before qks written
  f16*  xT      = (f16*)(ws + 67108864);         // 32 MB (64*1024*256*2)
  f16*  WkvT    = (f16*)(ws + 100663296);        // 2 MB
  f16*  WspecT  = (f16*)(ws + 102760448);        // 256 KB
  float* attnout = (float*)(ws + 103022592);     // 128 KB
  float* spatial = (float*)(ws + 103153664);     // 256 KB
  float* rvec    = (float*)(ws + 103415808);     // 256 KB
  (void)in_sizes; (void)n_in; (void)out_size; (void)ws_size;

  prep_xT    <<<dim3(32, 8, 64), dim3(256), 0, stream>>>(x, xT);
  prep_WkvT  <<<dim3(32, 32),    dim3(256), 0, stream>>>(Wkv, WkvT);
  prep_WspecT<<<dim3(16, 8),     dim3(256), 0, stream>>>(Wspec, WspecT);
  gemm_kv    <<<dim3(128, 8),    dim3(256), 0, stream>>>(x, WkvT, kv);
  qattn      <<<dim3(64, 8),     dim3(256), 0, stream>>>(x, Wq, kv, attnout);
  spatialk   <<<dim3(64),        dim3(256), 0, stream>>>(attnout, Wout, bout, spatial);
  gemm_qs    <<<dim3(8, 4, 64),  dim3(256), 0, stream>>>(xT, WspecT, qks);
  hipMemsetAsync(rvec, 0, 64*1024*sizeof(float), stream);
  speck      <<<dim3(32, 64),    dim3(256), 0, stream>>>(qks, spatial, rvec);
  bcast      <<<dim3(16384),     dim3(256), 0, stream>>>(rvec, out);
}

// Round 2
// 351.030 us; speedup vs baseline: 2.6375x; 2.6375x over previous
//
#include <hip/hip_runtime.h>
#include <hip/hip_bf16.h>
#include <cstdint>

typedef _Float16 f16;
typedef _Float16 half8 __attribute__((ext_vector_type(8)));
typedef float f32x4 __attribute__((ext_vector_type(4)));

#define SCALE 0.125f

// async global->LDS, 16B per lane, dest = wave-uniform base + lane*16
#define GLL(src, dst) __builtin_amdgcn_global_load_lds( \
    (const __attribute__((address_space(1))) unsigned int*)(src), \
    (__attribute__((address_space(3))) unsigned int*)(dst), 16, 0, 0)

// ---------------- prep: x f32 -> x16 f16 (row-major copy) ----------------
__global__ __launch_bounds__(256) void prep_x16(const float* __restrict__ x, f16* __restrict__ x16) {
  size_t i = ((size_t)blockIdx.x*256 + threadIdx.x)*8;
  f32x4 lo = *(const f32x4*)(x+i), hi = *(const f32x4*)(x+i+4);
  half8 h;
  h[0]=(f16)lo[0]; h[1]=(f16)lo[1]; h[2]=(f16)lo[2]; h[3]=(f16)lo[3];
  h[4]=(f16)hi[0]; h[5]=(f16)hi[1]; h[6]=(f16)hi[2]; h[7]=(f16)hi[3];
  *(half8*)(x16+i) = h;
}

// ---------------- prep: x (64,256,1024) f32 -> xT (64,1024,256) f16 ----------------
__global__ __launch_bounds__(256) void prep_xT(const float* __restrict__ x, f16* __restrict__ xT) {
  __shared__ float tile[32][33];
  int b = blockIdx.z, nt = blockIdx.y, dt = blockIdx.x;
  int c = threadIdx.x & 31, rp = threadIdx.x >> 5;
  const float* xb = x + ((size_t)b*256 + nt*32)*1024 + dt*32;
#pragma unroll
  for (int p = 0; p < 4; ++p) { int r = p*8 + rp; tile[r][c] = xb[(size_t)r*1024 + c]; }
  __syncthreads();
  f16* o = xT + ((size_t)b*1024 + dt*32)*256 + nt*32;
#pragma unroll
  for (int p = 0; p < 4; ++p) { int r = p*8 + rp; o[(size_t)r*256 + c] = (f16)tile[c][r]; }
}

// ---------------- prep: Wkv (1024,1024) f32 -> WkvT f16 ----
__global__ __launch_bounds__(256) void prep_WkvT(const float* __restrict__ W, f16* __restrict__ Wt) {
  __shared__ float tile[32][33];
  int kt = blockIdx.x, nt = blockIdx.y;
  int c = threadIdx.x & 31, rp = threadIdx.x >> 5;
#pragma unroll
  for (int p = 0; p < 4; ++p) { int r = p*8+rp; tile[r][c] = W[(size_t)(kt*32 + r)*1024 + nt*32 + c]; }
  __syncthreads();
#pragma unroll
  for (int p = 0; p < 4; ++p) { int r = p*8+rp; Wt[(size_t)(nt*32 + r)*1024 + kt*32 + c] = (f16)tile[c][r]; }
}

// ---------------- prep: Wspec (256,768) f32 -> WspecT (512,256) f16 ----
__global__ __launch_bounds__(256) void prep_WspecT(const float* __restrict__ W, f16* __restrict__ Wt) {
  __shared__ float tile[32][33];
  int jt = blockIdx.x, ct = blockIdx.y;
  int c = threadIdx.x & 31, rp = threadIdx.x >> 5;
#pragma unroll
  for (int p = 0; p < 4; ++p) { int r = p*8+rp; tile[r][c] = W[(size_t)(ct*32 + r)*768 + jt*32 + c]; }
  __syncthreads();
#pragma unroll
  for (int p = 0; p < 4; ++p) { int r = p*8+rp; Wt[(size_t)(jt*32 + r)*256 + ct*32 + c] = (f16)tile[c][r]; }
}

// ---------------- generic 128x128x(32*KSTEPS) f16 GEMM, LDS-staged, m97 structure ----
// A [M][AST] row-major (k contiguous), B [N][BST] row-major (k contiguous), C [M][CST] f16.
template<int KSTEPS, int AST, int BST, int CST>
__global__ __launch_bounds__(256) void gemm128(const f16* __restrict__ Ag, const f16* __restrict__ Bg,
                                               f16* __restrict__ Cg, size_t aB, size_t bB, size_t cB) {
  __shared__ f16 As[128*32];
  __shared__ f16 Bs[128*32];
  const f16* A = Ag + (size_t)blockIdx.z*aB;
  const f16* B = Bg + (size_t)blockIdx.z*bB;
  f16* C = Cg + (size_t)blockIdx.z*cB;
  int t = threadIdx.x, lane = t & 63, wave = t >> 6;
  int l15 = lane & 15, l4 = lane >> 4;
  int wm = wave & 1, wn = wave >> 1;
  size_t m0 = (size_t)blockIdx.x*128, n0 = (size_t)blockIdx.y*128;
  f32x4 acc[4][4];
#pragma unroll
  for (int i=0;i<4;++i)
#pragma unroll
    for (int j=0;j<4;++j) acc[i][j] = (f32x4){0.f,0.f,0.f,0.f};
  // staging slots (16B units): slot = c*256 + t; row = slot>>2; phys chunk slot&3 holds logical (slot&3)^((slot>>3)&3)
  int rowS[2], chS[2];
#pragma unroll
  for (int c=0;c<2;++c) {
    int slot = c*256 + t;
    rowS[c] = slot >> 2;
    chS[c]  = (slot & 3) ^ ((slot >> 3) & 3);
  }
  // fragment read: logical chunk l4 of row (base+l15) lives at phys chunk l4^((l15>>1)&3)
  int pc = (l4 ^ ((l15 >> 1) & 3)) * 8;
  const f16* Afr = As + (wm*64 + l15)*32 + pc;
  const f16* Bfr = Bs + (wn*64 + l15)*32 + pc;
  for (int ks = 0; ks < KSTEPS; ++ks) {
    int k0 = ks*32;
#pragma unroll
    for (int c=0;c<2;++c) {
      GLL(A + (m0 + rowS[c])*(size_t)AST + k0 + chS[c]*8, &As[(c*256 + wave*64)*8]);
      GLL(B + (n0 + rowS[c])*(size_t)BST + k0 + chS[c]*8, &Bs[(c*256 + wave*64)*8]);
    }
    __syncthreads();
    half8 a[4], bb[4];
#pragma unroll
    for (int mi=0;mi<4;++mi) a[mi]  = *(const half8*)(Afr + mi*16*32);
#pragma unroll
    for (int ni=0;ni<4;++ni) bb[ni] = *(const half8*)(Bfr + ni*16*32);
#pragma unroll
    for (int mi=0;mi<4;++mi)
#pragma unroll
      for (int ni=0;ni<4;++ni)
        acc[mi][ni] = __builtin_amdgcn_mfma_f32_16x16x32_f16(a[mi], bb[ni], acc[mi][ni], 0,0,0);
    __syncthreads();
  }
#pragma unroll
  for (int mi=0;mi<4;++mi)
#pragma unroll
    for (int ni=0;ni<4;++ni)
#pragma unroll
      for (int j=0;j<4;++j) {
        size_t row = m0 + wm*64 + mi*16 + 4*l4 + j;
        size_t col = n0 + wn*64 + ni*16 + l15;
        C[row*CST + col] = (f16)acc[mi][ni][j];
      }
}

// ---------------- qattn: per (b,h): q = x_center @ Wq, attn over 256, out -> attnout (64,512) f32 ----
__global__ __launch_bounds__(256) void qattn(const float* __restrict__ x, const float* __restrict__ Wq,
                                             const f16* __restrict__ kv, float* __restrict__ attnout) {
  int b = blockIdx.x, h = blockIdx.y;
  int t = threadIdx.x;
  __shared__ float xc[1024];
  __shared__ float qh[64];
  __shared__ float p[256];
  __shared__ float part[4][64];
  __shared__ float redw[4];
  const float* xcg = x + ((size_t)b*256 + 128)*1024;
#pragma unroll
  for (int i = 0; i < 4; ++i) xc[t + 256*i] = xcg[t + 256*i];
  __syncthreads();
  int d = t & 63, chunk = t >> 6;
  {
    float s = 0.f;
    const float* wq = Wq + (size_t)(chunk*256)*512 + h*64 + d;
    for (int c = 0; c < 256; ++c) s += xc[chunk*256 + c] * wq[(size_t)c*512];
    part[chunk][d] = s;
  }
  __syncthreads();
  if (t < 64) qh[t] = part[0][t]+part[1][t]+part[2][t]+part[3][t];
  __syncthreads();
  {
    const f16* kp = kv + ((size_t)b*256 + t)*1024 + h*64;
    float acc = 0.f;
#pragma unroll
    for (int d8 = 0; d8 < 8; ++d8) {
      half8 kk = *(const half8*)(kp + d8*8);
#pragma unroll
      for (int j = 0; j < 8; ++j) acc += (float)kk[j] * qh[d8*8+j];
    }
    p[t] = acc * SCALE;
  }
  __syncthreads();
  int lane = t & 63, wid = t >> 6;
  float v = p[t];
#pragma unroll
  for (int o = 32; o >= 1; o >>= 1) v = fmaxf(v, __shfl_xor(v, o));
  if (lane == 0) redw[wid] = v;
  __syncthreads();
  float m = fmaxf(fmaxf(redw[0],redw[1]),fmaxf(redw[2],redw[3]));
  float e = __expf(p[t] - m);
  __syncthreads();
  v = e;
#pragma unroll
  for (int o = 32; o >= 1; o >>= 1) v += __shfl_xor(v, o);
  if (lane == 0) redw[wid] = v;
  __syncthreads();
  float Z = redw[0]+redw[1]+redw[2]+redw[3];
  p[t] = e / Z;
  __syncthreads();
  {
    float o = 0.f;
    const f16* vp = kv + ((size_t)b*256 + chunk*64)*1024 + 512 + h*64 + d;
    for (int n = 0; n < 64; ++n) o += p[chunk*64 + n] * (float)vp[(size_t)n*1024];
    part[chunk][d] = o;
  }
  __syncthreads();
  if (t < 64) attnout[(size_t)b*512 + h*64 + t] = part[0][t]+part[1][t]+part[2][t]+part[3][t];
}

// ---------------- spatial: (64,512) @ Wout (512,1024) + bout -> spatial (64,1024) f32 ----------
__global__ __launch_bounds__(256) void spatialk(const float* __restrict__ attnout, const float* __restrict__ Wout,
                                                const float* __restrict__ bout, float* __restrict__ spatial) {
  int b = blockIdx.x, t = threadIdx.x;
  __shared__ float ao[512];
  ao[t] = attnout[(size_t)b*512 + t];
  ao[t+256] = attnout[(size_t)b*512 + 256 + t];
  __syncthreads();
#pragma unroll
  for (int rep = 0; rep < 4; ++rep) {
    int e = rep*256 + t;
    float acc = bout[e];
#pragma unroll 8
    for (int i = 0; i < 512; ++i) acc += ao[i] * Wout[(size_t)i*1024 + e];
    spatial[(size_t)b*1024 + e] = acc;
  }
}

// ---------------- spec: per (b, 64-row i-block): L = q_s @ k_s^T * S, row-softmax, r += spatial.w ----
// 512 threads = 8 waves: wave = (eh<<2)|iw; wave covers i-rows i0..i0+15, e-half eh (512 e).
// k_s tile (1024 rows x 32 k) staged to LDS per k-step via global_load_lds + source XOR swizzle.
__global__ __launch_bounds__(512) void speck(const f16* __restrict__ qks, const float* __restrict__ spatial,
                                             float* __restrict__ r) {
  __shared__ f16 Bs[1024*32];          // 64 KB
  __shared__ float sm[4][2][16];
  __shared__ float sz[4][2][16];
  int iblk = blockIdx.x, b = blockIdx.y;
  int t = threadIdx.x, lane = t & 63, wave = t >> 6;
  int l15 = lane & 15, l4 = lane >> 4;
  int iw = wave & 3, eh = wave >> 2;
  const f16* qs = qks + (size_t)b*1024*512;
  int i0 = iblk*64 + iw*16;
  // A (q_s rows) prefetch to registers: 16 rows x 256 k per wave
  half8 a[8];
  const f16* Ap = qs + (size_t)(i0 + l15)*512 + 8*l4;
#pragma unroll
  for (int ks = 0; ks < 8; ++ks) a[ks] = *(const half8*)(Ap + ks*32);
  f32x4 acc[32];
#pragma unroll
  for (int tt=0;tt<32;++tt) acc[tt] = (f32x4){0.f,0.f,0.f,0.f};
  int pc = (l4 ^ ((l15 >> 1) & 3)) * 8;
  const f16* Bfr = Bs + (eh*512 + l15)*32 + pc;
  for (int ks = 0; ks < 8; ++ks) {
    int k0 = ks*32;
#pragma unroll
    for (int c = 0; c < 8; ++c) {
      int slot = c*512 + t;
      int row = slot >> 2;
      int ch = (slot & 3) ^ ((slot >> 3) & 3);
      GLL(qs + 256 + (size_t)row*512 + k0 + ch*8, &Bs[(c*512 + wave*64)*8]);
    }
    __syncthreads();
#pragma unroll
    for (int tt = 0; tt < 32; ++tt) {
      half8 bb = *(const half8*)(Bfr + tt*16*32);
      acc[tt] = __builtin_amdgcn_mfma_f32_16x16x32_f16(a[ks], bb, acc[tt], 0,0,0);
    }
    __syncthreads();
  }
  // scale
#pragma unroll
  for (int tt=0;tt<32;++tt)
#pragma unroll
    for (int j=0;j<4;++j) acc[tt][j] *= SCALE;
  // row max over this wave's 512 cols
  float m[4] = {-1e30f,-1e30f,-1e30f,-1e30f};
#pragma unroll
  for (int tt=0;tt<32;++tt)
#pragma unroll
    for (int j=0;j<4;++j) m[j] = fmaxf(m[j], acc[tt][j]);
#pragma unroll
  for (int o = 1; o < 16; o <<= 1)
#pragma unroll
    for (int j=0;j<4;++j) m[j] = fmaxf(m[j], __shfl_xor(m[j], o));
  if (l15 == 0) {
#pragma unroll
    for (int j=0;j<4;++j) sm[iw][eh][4*l4+j] = m[j];
  }
  __syncthreads();
#pragma unroll
  for (int j=0;j<4;++j) m[j] = fmaxf(sm[iw][0][4*l4+j], sm[iw][1][4*l4+j]);
  // exp + row sum
  float z[4] = {0.f,0.f,0.f,0.f};
#pragma unroll
  for (int tt=0;tt<32;++tt)
#pragma unroll
    for (int j=0;j<4;++j) { float e = __expf(acc[tt][j] - m[j]); acc[tt][j] = e; z[j] += e; }
#pragma unroll
  for (int o = 1; o < 16; o <<= 1)
#pragma unroll
    for (int j=0;j<4;++j) z[j] += __shfl_xor(z[j], o);
  if (l15 == 0) {
#pragma unroll
    for (int j=0;j<4;++j) sz[iw][eh][4*l4+j] = z[j];
  }
  __syncthreads();
  float f[4];
#pragma unroll
  for (int j=0;j<4;++j) {
    float zz = sz[iw][0][4*l4+j] + sz[iw][1][4*l4+j];
    f[j] = spatial[(size_t)b*1024 + i0 + 4*l4 + j] / zz;
  }
  float* rb = r + (size_t)b*1024;
#pragma unroll
  for (int tt=0;tt<32;++tt) {
    float v = f[0]*acc[tt][0] + f[1]*acc[tt][1] + f[2]*acc[tt][2] + f[3]*acc[tt][3];
    v += __shfl_xor(v, 16);
    v += __shfl_xor(v, 32);
    if (l4 == 0) atomicAdd(rb + eh*512 + tt*16 + l15, v);
  }
}

// ---------------- broadcast: out[b,n,:] = r[b,:] ----------------
__global__ __launch_bounds__(256) void bcast(const float* __restrict__ r, float* __restrict__ out) {
  size_t row = blockIdx.x;
  int b = (int)(row >> 8);
  f32x4 v = *(const f32x4*)(r + (size_t)b*1024 + threadIdx.x*4);
  *(f32x4*)(out + row*1024 + (size_t)threadIdx.x*4) = v;
}

extern "C" void kernel_launch(void* const* d_in, const int* in_sizes, int n_in,
                              void* d_out, int out_size, void* d_ws, size_t ws_size,
                              hipStream_t stream) {
  const float* x     = (const float*)d_in[0];
  const float* Wq    = (const float*)d_in[1];
  const float* Wkv   = (const float*)d_in[2];
  const float* Wout  = (const float*)d_in[3];
  const float* bout  = (const float*)d_in[4];
  const float* Wspec = (const float*)d_in[5];
  float* out = (float*)d_out;
  char* ws = (char*)d_ws;
  // workspace (~103.7 MB):
  //   qks  @0       64MB   (written by gemm_qs, read by speck)
  //   kv   @0       32MB   alias of qks[0:32M] — dead before gemm_qs writes
  //   x16  @32M     32MB   alias of qks[32M:64M] — dead after gemm_kv (before gemm_qs writes)
  f16*  qks     = (f16*)(ws);
  f16*  kv      = (f16*)(ws);
  f16*  x16     = (f16*)(ws + 33554432);
  f16*  xT      = (f16*)(ws + 67108864);         // 32 MB
  f16*  WkvT    = (f16*)(ws + 100663296);        // 2 MB
  f16*  WspecT  = (f16*)(ws + 102760448);        // 256 KB
  float* attnout = (float*)(ws + 103022592);     // 128 KB
  float* spatial = (float*)(ws + 103153664);     // 256 KB
  float* rvec    = (float*)(ws + 103415808);     // 256 KB
  (void)in_sizes; (void)n_in; (void)out_size; (void)ws_size;

  prep_x16   <<<dim3(8192),      dim3(256), 0, stream>>>(x, x16);
  prep_xT    <<<dim3(32, 8, 64), dim3(256), 0, stream>>>(x, xT);
  prep_WkvT  <<<dim3(32, 32),    dim3(256), 0, stream>>>(Wkv, WkvT);
  prep_WspecT<<<dim3(16, 8),     dim3(256), 0, stream>>>(Wspec, WspecT);
  // kv = x16 (16384x1024) @ WkvT^T : K=1024
  gemm128<32,1024,1024,1024><<<dim3(128, 8, 1), dim3(256), 0, stream>>>(x16, WkvT, kv, 0, 0, 0);
  qattn      <<<dim3(64, 8),     dim3(256), 0, stream>>>(x, Wq, kv, attnout);
  spatialk   <<<dim3(64),        dim3(256), 0, stream>>>(attnout, Wout, bout, spatial);
  // qks[b] = xT[b] (1024x256) @ WspecT^T : K=256
  gemm128<8,256,256,512><<<dim3(8, 4, 64), dim3(256), 0, stream>>>(xT, WspecT, qks,
                                                                   (size_t)1024*256, 0, (size_t)1024*512);
  hipMemsetAsync(rvec, 0, 64*1024*sizeof(float), stream);
  speck      <<<dim3(16, 64),    dim3(512), 0, stream>>>(qks, spatial, rvec);
  bcast      <<<dim3(16384),     dim3(256), 0, stream>>>(rvec, out);
}

// Round 3
// 271.385 us; speedup vs baseline: 3.4115x; 1.2935x over previous
//
#include <hip/hip_runtime.h>
#include <hip/hip_bf16.h>
#include <cstdint>

typedef _Float16 f16;
typedef _Float16 half8 __attribute__((ext_vector_type(8)));
typedef float f32x4 __attribute__((ext_vector_type(4)));

#define SCALE 0.125f

// async global->LDS, 16B per lane, dest = wave-uniform base + lane*16
#define GLL(src, dst) __builtin_amdgcn_global_load_lds( \
    (const __attribute__((address_space(1))) unsigned int*)(src), \
    (__attribute__((address_space(3))) unsigned int*)(dst), 16, 0, 0)

// ---------------- prep: x f32 -> x16 f16 (row-major copy) ----------------
__global__ __launch_bounds__(256) void prep_x16(const float* __restrict__ x, f16* __restrict__ x16) {
  size_t i = ((size_t)blockIdx.x*256 + threadIdx.x)*8;
  f32x4 lo = *(const f32x4*)(x+i), hi = *(const f32x4*)(x+i+4);
  half8 h;
  h[0]=(f16)lo[0]; h[1]=(f16)lo[1]; h[2]=(f16)lo[2]; h[3]=(f16)lo[3];
  h[4]=(f16)hi[0]; h[5]=(f16)hi[1]; h[6]=(f16)hi[2]; h[7]=(f16)hi[3];
  *(half8*)(x16+i) = h;
}

// ---------------- prep: x16 (64,256,1024) f16 -> xT (64,1024,256) f16 ----------------
__global__ __launch_bounds__(256) void prep_xT(const f16* __restrict__ x16, f16* __restrict__ xT) {
  __shared__ f16 tile[32][33];
  int b = blockIdx.z, nt = blockIdx.y, dt = blockIdx.x;
  int c = threadIdx.x & 31, rp = threadIdx.x >> 5;
  const f16* xb = x16 + ((size_t)b*256 + nt*32)*1024 + dt*32;
#pragma unroll
  for (int p = 0; p < 4; ++p) { int r = p*8 + rp; tile[r][c] = xb[(size_t)r*1024 + c]; }
  __syncthreads();
  f16* o = xT + ((size_t)b*1024 + dt*32)*256 + nt*32;
#pragma unroll
  for (int p = 0; p < 4; ++p) { int r = p*8 + rp; o[(size_t)r*256 + c] = tile[c][r]; }
}

// ---------------- prep: Wkv (1024,1024) f32 -> WkvT f16 ----
__global__ __launch_bounds__(256) void prep_WkvT(const float* __restrict__ W, f16* __restrict__ Wt) {
  __shared__ float tile[32][33];
  int kt = blockIdx.x, nt = blockIdx.y;
  int c = threadIdx.x & 31, rp = threadIdx.x >> 5;
#pragma unroll
  for (int p = 0; p < 4; ++p) { int r = p*8+rp; tile[r][c] = W[(size_t)(kt*32 + r)*1024 + nt*32 + c]; }
  __syncthreads();
#pragma unroll
  for (int p = 0; p < 4; ++p) { int r = p*8+rp; Wt[(size_t)(nt*32 + r)*1024 + kt*32 + c] = (f16)tile[c][r]; }
}

// ---------------- prep: Wspec (256,768) f32 -> WspecT (512,256) f16 ----
__global__ __launch_bounds__(256) void prep_WspecT(const float* __restrict__ W, f16* __restrict__ Wt) {
  __shared__ float tile[32][33];
  int jt = blockIdx.x, ct = blockIdx.y;
  int c = threadIdx.x & 31, rp = threadIdx.x >> 5;
#pragma unroll
  for (int p = 0; p < 4; ++p) { int r = p*8+rp; tile[r][c] = W[(size_t)(ct*32 + r)*768 + jt*32 + c]; }
  __syncthreads();
#pragma unroll
  for (int p = 0; p < 4; ++p) { int r = p*8+rp; Wt[(size_t)(jt*32 + r)*256 + ct*32 + c] = (f16)tile[c][r]; }
}

// ---------------- generic 128x128x(32*KSTEPS) f16 GEMM, LDS-staged, m97 structure ----
template<int KSTEPS, int AST, int BST, int CST>
__global__ __launch_bounds__(256) void gemm128(const f16* __restrict__ Ag, const f16* __restrict__ Bg,
                                               f16* __restrict__ Cg, size_t aB, size_t bB, size_t cB) {
  __shared__ f16 As[128*32];
  __shared__ f16 Bs[128*32];
  const f16* A = Ag + (size_t)blockIdx.z*aB;
  const f16* B = Bg + (size_t)blockIdx.z*bB;
  f16* C = Cg + (size_t)blockIdx.z*cB;
  int t = threadIdx.x, lane = t & 63, wave = t >> 6;
  int l15 = lane & 15, l4 = lane >> 4;
  int wm = wave & 1, wn = wave >> 1;
  size_t m0 = (size_t)blockIdx.x*128, n0 = (size_t)blockIdx.y*128;
  f32x4 acc[4][4];
#pragma unroll
  for (int i=0;i<4;++i)
#pragma unroll
    for (int j=0;j<4;++j) acc[i][j] = (f32x4){0.f,0.f,0.f,0.f};
  int rowS[2], chS[2];
#pragma unroll
  for (int c=0;c<2;++c) {
    int slot = c*256 + t;
    rowS[c] = slot >> 2;
    chS[c]  = (slot & 3) ^ ((slot >> 3) & 3);
  }
  int pc = (l4 ^ ((l15 >> 1) & 3)) * 8;
  const f16* Afr = As + (wm*64 + l15)*32 + pc;
  const f16* Bfr = Bs + (wn*64 + l15)*32 + pc;
  for (int ks = 0; ks < KSTEPS; ++ks) {
    int k0 = ks*32;
#pragma unroll
    for (int c=0;c<2;++c) {
      GLL(A + (m0 + rowS[c])*(size_t)AST + k0 + chS[c]*8, &As[(c*256 + wave*64)*8]);
      GLL(B + (n0 + rowS[c])*(size_t)BST + k0 + chS[c]*8, &Bs[(c*256 + wave*64)*8]);
    }
    __syncthreads();
    half8 a[4], bb[4];
#pragma unroll
    for (int mi=0;mi<4;++mi) a[mi]  = *(const half8*)(Afr + mi*16*32);
#pragma unroll
    for (int ni=0;ni<4;++ni) bb[ni] = *(const half8*)(Bfr + ni*16*32);
#pragma unroll
    for (int mi=0;mi<4;++mi)
#pragma unroll
      for (int ni=0;ni<4;++ni)
        acc[mi][ni] = __builtin_amdgcn_mfma_f32_16x16x32_f16(a[mi], bb[ni], acc[mi][ni], 0,0,0);
    __syncthreads();
  }
#pragma unroll
  for (int mi=0;mi<4;++mi)
#pragma unroll
    for (int ni=0;ni<4;++ni)
#pragma unroll
      for (int j=0;j<4;++j) {
        size_t row = m0 + wm*64 + mi*16 + 4*l4 + j;
        size_t col = n0 + wn*64 + ni*16 + l15;
        C[row*CST + col] = (f16)acc[mi][ni][j];
      }
}

// ---------------- qattn: per (b,h): q = x_center @ Wq, attn over 256, out -> attnout (64,512) f32 ----
__global__ __launch_bounds__(256) void qattn(const float* __restrict__ x, const float* __restrict__ Wq,
                                             const f16* __restrict__ kv, float* __restrict__ attnout) {
  int b = blockIdx.x, h = blockIdx.y;
  int t = threadIdx.x;
  __shared__ float xc[1024];
  __shared__ float qh[64];
  __shared__ float p[256];
  __shared__ float part[4][64];
  __shared__ float redw[4];
  const float* xcg = x + ((size_t)b*256 + 128)*1024;
#pragma unroll
  for (int i = 0; i < 4; ++i) xc[t + 256*i] = xcg[t + 256*i];
  __syncthreads();
  int d = t & 63, chunk = t >> 6;
  {
    float s = 0.f;
    const float* wq = Wq + (size_t)(chunk*256)*512 + h*64 + d;
#pragma unroll 8
    for (int c = 0; c < 256; ++c) s += xc[chunk*256 + c] * wq[(size_t)c*512];
    part[chunk][d] = s;
  }
  __syncthreads();
  if (t < 64) qh[t] = part[0][t]+part[1][t]+part[2][t]+part[3][t];
  __syncthreads();
  {
    const f16* kp = kv + ((size_t)b*256 + t)*1024 + h*64;
    float acc = 0.f;
#pragma unroll
    for (int d8 = 0; d8 < 8; ++d8) {
      half8 kk = *(const half8*)(kp + d8*8);
#pragma unroll
      for (int j = 0; j < 8; ++j) acc += (float)kk[j] * qh[d8*8+j];
    }
    p[t] = acc * SCALE;
  }
  __syncthreads();
  int lane = t & 63, wid = t >> 6;
  float v = p[t];
#pragma unroll
  for (int o = 32; o >= 1; o >>= 1) v = fmaxf(v, __shfl_xor(v, o));
  if (lane == 0) redw[wid] = v;
  __syncthreads();
  float m = fmaxf(fmaxf(redw[0],redw[1]),fmaxf(redw[2],redw[3]));
  float e = __expf(p[t] - m);
  __syncthreads();
  v = e;
#pragma unroll
  for (int o = 32; o >= 1; o >>= 1) v += __shfl_xor(v, o);
  if (lane == 0) redw[wid] = v;
  __syncthreads();
  float Z = redw[0]+redw[1]+redw[2]+redw[3];
  p[t] = e / Z;
  __syncthreads();
  {
    float o = 0.f;
    const f16* vp = kv + ((size_t)b*256 + chunk*64)*1024 + 512 + h*64 + d;
#pragma unroll 8
    for (int n = 0; n < 64; ++n) o += p[chunk*64 + n] * (float)vp[(size_t)n*1024];
    part[chunk][d] = o;
  }
  __syncthreads();
  if (t < 64) attnout[(size_t)b*512 + h*64 + t] = part[0][t]+part[1][t]+part[2][t]+part[3][t];
}

// ---------------- spatial partial: block (ic, b): partial[b][ic][e] = sum_{i in chunk} ao[i]*Wout[i][e]
__global__ __launch_bounds__(256) void spatialp(const float* __restrict__ attnout, const float* __restrict__ Wout,
                                                float* __restrict__ partial) {
  int ic = blockIdx.x, b = blockIdx.y;
  int t = threadIdx.x;
  __shared__ float ao[128];
  if (t < 128) ao[t] = attnout[(size_t)b*512 + ic*128 + t];
  __syncthreads();
  const float* W = Wout + (size_t)ic*128*1024 + t*4;
  f32x4 acc0 = (f32x4){0.f,0.f,0.f,0.f};
  f32x4 acc1 = (f32x4){0.f,0.f,0.f,0.f};
#pragma unroll 4
  for (int i = 0; i < 128; i += 2) {
    f32x4 w0 = *(const f32x4*)(W + (size_t)i*1024);
    f32x4 w1 = *(const f32x4*)(W + (size_t)(i+1)*1024);
    float a0 = ao[i], a1 = ao[i+1];
    acc0[0] += a0*w0[0]; acc0[1] += a0*w0[1]; acc0[2] += a0*w0[2]; acc0[3] += a0*w0[3];
    acc1[0] += a1*w1[0]; acc1[1] += a1*w1[1]; acc1[2] += a1*w1[2]; acc1[3] += a1*w1[3];
  }
  f32x4 acc;
#pragma unroll
  for (int j=0;j<4;++j) acc[j] = acc0[j] + acc1[j];
  *(f32x4*)(partial + ((size_t)(b*4 + ic))*1024 + t*4) = acc;
}

// ---------------- spatial reduce: spatial[b][e] = bout[e] + sum_ic partial[b][ic][e] ----
__global__ __launch_bounds__(256) void spatialr(const float* __restrict__ partial, const float* __restrict__ bout,
                                                float* __restrict__ spatial) {
  int b = blockIdx.x, t = threadIdx.x;
  f32x4 s = *(const f32x4*)(bout + t*4);
#pragma unroll
  for (int ic = 0; ic < 4; ++ic) {
    f32x4 p = *(const f32x4*)(partial + ((size_t)(b*4 + ic))*1024 + t*4);
#pragma unroll
    for (int j=0;j<4;++j) s[j] += p[j];
  }
  *(f32x4*)(spatial + (size_t)b*1024 + t*4) = s;
}

// ---------------- spec: per (b, 64-row i-block): L = q_s @ k_s^T * S, row-softmax, r += spatial.w ----
__global__ __launch_bounds__(512) void speck(const f16* __restrict__ qks, const float* __restrict__ spatial,
                                             float* __restrict__ r) {
  __shared__ f16 Bs[1024*32];          // 64 KB
  __shared__ float sm[4][2][16];
  __shared__ float sz[4][2][16];
  int iblk = blockIdx.x, b = blockIdx.y;
  int t = threadIdx.x, lane = t & 63, wave = t >> 6;
  int l15 = lane & 15, l4 = lane >> 4;
  int iw = wave & 3, eh = wave >> 2;
  const f16* qs = qks + (size_t)b*1024*512;
  int i0 = iblk*64 + iw*16;
  half8 a[8];
  const f16* Ap = qs + (size_t)(i0 + l15)*512 + 8*l4;
#pragma unroll
  for (int ks = 0; ks < 8; ++ks) a[ks] = *(const half8*)(Ap + ks*32);
  f32x4 acc[32];
#pragma unroll
  for (int tt=0;tt<32;++tt) acc[tt] = (f32x4){0.f,0.f,0.f,0.f};
  int pc = (l4 ^ ((l15 >> 1) & 3)) * 8;
  const f16* Bfr = Bs + (eh*512 + l15)*32 + pc;
  for (int ks = 0; ks < 8; ++ks) {
    int k0 = ks*32;
#pragma unroll
    for (int c = 0; c < 8; ++c) {
      int slot = c*512 + t;
      int row = slot >> 2;
      int ch = (slot & 3) ^ ((slot >> 3) & 3);
      GLL(qs + 256 + (size_t)row*512 + k0 + ch*8, &Bs[(c*512 + wave*64)*8]);
    }
    __syncthreads();
#pragma unroll
    for (int tt = 0; tt < 32; ++tt) {
      half8 bb = *(const half8*)(Bfr + tt*16*32);
      acc[tt] = __builtin_amdgcn_mfma_f32_16x16x32_f16(a[ks], bb, acc[tt], 0,0,0);
    }
    __syncthreads();
  }
#pragma unroll
  for (int tt=0;tt<32;++tt)
#pragma unroll
    for (int j=0;j<4;++j) acc[tt][j] *= SCALE;
  float m[4] = {-1e30f,-1e30f,-1e30f,-1e30f};
#pragma unroll
  for (int tt=0;tt<32;++tt)
#pragma unroll
    for (int j=0;j<4;++j) m[j] = fmaxf(m[j], acc[tt][j]);
#pragma unroll
  for (int o = 1; o < 16; o <<= 1)
#pragma unroll
    for (int j=0;j<4;++j) m[j] = fmaxf(m[j], __shfl_xor(m[j], o));
  if (l15 == 0) {
#pragma unroll
    for (int j=0;j<4;++j) sm[iw][eh][4*l4+j] = m[j];
  }
  __syncthreads();
#pragma unroll
  for (int j=0;j<4;++j) m[j] = fmaxf(sm[iw][0][4*l4+j], sm[iw][1][4*l4+j]);
  float z[4] = {0.f,0.f,0.f,0.f};
#pragma unroll
  for (int tt=0;tt<32;++tt)
#pragma unroll
    for (int j=0;j<4;++j) { float e = __expf(acc[tt][j] - m[j]); acc[tt][j] = e; z[j] += e; }
#pragma unroll
  for (int o = 1; o < 16; o <<= 1)
#pragma unroll
    for (int j=0;j<4;++j) z[j] += __shfl_xor(z[j], o);
  if (l15 == 0) {
#pragma unroll
    for (int j=0;j<4;++j) sz[iw][eh][4*l4+j] = z[j];
  }
  __syncthreads();
  float f[4];
#pragma unroll
  for (int j=0;j<4;++j) {
    float zz = sz[iw][0][4*l4+j] + sz[iw][1][4*l4+j];
    f[j] = spatial[(size_t)b*1024 + i0 + 4*l4 + j] / zz;
  }
  float* rb = r + (size_t)b*1024;
#pragma unroll
  for (int tt=0;tt<32;++tt) {
    float v = f[0]*acc[tt][0] + f[1]*acc[tt][1] + f[2]*acc[tt][2] + f[3]*acc[tt][3];
    v += __shfl_xor(v, 16);
    v += __shfl_xor(v, 32);
    if (l4 == 0) atomicAdd(rb + eh*512 + tt*16 + l15, v);
  }
}

// ---------------- broadcast: out[b,n,:] = r[b,:] ----------------
__global__ __launch_bounds__(256) void bcast(const float* __restrict__ r, float* __restrict__ out) {
  size_t row = blockIdx.x;
  int b = (int)(row >> 8);
  f32x4 v = *(const f32x4*)(r + (size_t)b*1024 + threadIdx.x*4);
  *(f32x4*)(out + row*1024 + (size_t)threadIdx.x*4) = v;
}

extern "C" void kernel_launch(void* const* d_in, const int* in_sizes, int n_in,
                              void* d_out, int out_size, void* d_ws, size_t ws_size,
                              hipStream_t stream) {
  const float* x     = (const float*)d_in[0];
  const float* Wq    = (const float*)d_in[1];
  const float* Wkv   = (const float*)d_in[2];
  const float* Wout  = (const float*)d_in[3];
  const float* bout  = (const float*)d_in[4];
  const float* Wspec = (const float*)d_in[5];
  float* out = (float*)d_out;
  char* ws = (char*)d_ws;
  // workspace (~98.9 MB), with time-multiplexed aliases (stream-ordered, safe):
  //   qks  @0       64MB   (written by gemm_qs, read by speck)
  //   kv   @0       32MB   alias — dead after qattn, before gemm_qs writes
  //   partial @0     1MB   alias — written by spatialp after qattn, read by spatialr before gemm_qs
  //   x16  @32M     32MB   alias of qks[32M:64M] — dead after gemm_kv, before gemm_qs writes
  f16*  qks     = (f16*)(ws);
  f16*  kv      = (f16*)(ws);
  float* partial = (float*)(ws);
  f16*  x16     = (f16*)(ws + 33554432);
  f16*  xT      = (f16*)(ws + 67108864);         // 32 MB
  f16*  WkvT    = (f16*)(ws + 100663296);        // 2 MB
  f16*  WspecT  = (f16*)(ws + 102760448);        // 256 KB
  float* attnout = (float*)(ws + 103022592);     // 128 KB
  float* spatial = (float*)(ws + 103153664);     // 256 KB
  float* rvec    = (float*)(ws + 103415808);     // 256 KB
  (void)in_sizes; (void)n_in; (void)out_size; (void)ws_size;

  prep_x16   <<<dim3(8192),      dim3(256), 0, stream>>>(x, x16);
  prep_xT    <<<dim3(32, 8, 64), dim3(256), 0, stream>>>(x16, xT);
  prep_WkvT  <<<dim3(32, 32),    dim3(256), 0, stream>>>(Wkv, WkvT);
  prep_WspecT<<<dim3(16, 8),     dim3(256), 0, stream>>>(Wspec, WspecT);
  // kv = x16 (16384x1024) @ WkvT^T : K=1024
  gemm128<32,1024,1024,1024><<<dim3(128, 8, 1), dim3(256), 0, stream>>>(x16, WkvT, kv, 0, 0, 0);
  qattn      <<<dim3(64, 8),     dim3(256), 0, stream>>>(x, Wq, kv, attnout);
  spatialp   <<<dim3(4, 64),     dim3(256), 0, stream>>>(attnout, Wout, partial);
  spatialr   <<<dim3(64),        dim3(256), 0, stream>>>(partial, bout, spatial);
  // qks[b] = xT[b] (1024x256) @ WspecT^T : K=256
  gemm128<8,256,256,512><<<dim3(8, 4, 64), dim3(256), 0, stream>>>(xT, WspecT, qks,
                                                                   (size_t)1024*256, 0, (size_t)1024*512);
  hipMemsetAsync(rvec, 0, 64*1024*sizeof(float), stream);
  speck      <<<dim3(16, 64),    dim3(512), 0, stream>>>(qks, spatial, rvec);
  bcast      <<<dim3(16384),     dim3(256), 0, stream>>>(rvec, out);
}

// Round 4
// 254.405 us; speedup vs baseline: 3.6392x; 1.0667x over previous
//
#include <hip/hip_runtime.h>
#include <hip/hip_bf16.h>
#include <cstdint>

typedef _Float16 f16;
typedef _Float16 half8 __attribute__((ext_vector_type(8)));
typedef float f32x4 __attribute__((ext_vector_type(4)));

#define SCALE 0.125f

// async global->LDS, 16B per lane, dest = wave-uniform base + lane*16
#define GLL(src, dst) __builtin_amdgcn_global_load_lds( \
    (const __attribute__((address_space(1))) unsigned int*)(src), \
    (__attribute__((address_space(3))) unsigned int*)(dst), 16, 0, 0)

// ---------------- prep: x f32 -> x16 f16 (row-major copy) ----------------
__global__ __launch_bounds__(256) void prep_x16(const float* __restrict__ x, f16* __restrict__ x16) {
  size_t i = ((size_t)blockIdx.x*256 + threadIdx.x)*8;
  f32x4 lo = *(const f32x4*)(x+i), hi = *(const f32x4*)(x+i+4);
  half8 h;
  h[0]=(f16)lo[0]; h[1]=(f16)lo[1]; h[2]=(f16)lo[2]; h[3]=(f16)lo[3];
  h[4]=(f16)hi[0]; h[5]=(f16)hi[1]; h[6]=(f16)hi[2]; h[7]=(f16)hi[3];
  *(half8*)(x16+i) = h;
}

// ---------------- prep: x16 (64,256,1024) f16 -> xT (64,1024,256) f16 ----------------
__global__ __launch_bounds__(256) void prep_xT(const f16* __restrict__ x16, f16* __restrict__ xT) {
  __shared__ f16 tile[32][33];
  int b = blockIdx.z, nt = blockIdx.y, dt = blockIdx.x;
  int c = threadIdx.x & 31, rp = threadIdx.x >> 5;
  const f16* xb = x16 + ((size_t)b*256 + nt*32)*1024 + dt*32;
#pragma unroll
  for (int p = 0; p < 4; ++p) { int r = p*8 + rp; tile[r][c] = xb[(size_t)r*1024 + c]; }
  __syncthreads();
  f16* o = xT + ((size_t)b*1024 + dt*32)*256 + nt*32;
#pragma unroll
  for (int p = 0; p < 4; ++p) { int r = p*8 + rp; o[(size_t)r*256 + c] = tile[c][r]; }
}

// ---------------- prep: Wkv (1024,1024) f32 -> WkvT f16 ----
__global__ __launch_bounds__(256) void prep_WkvT(const float* __restrict__ W, f16* __restrict__ Wt) {
  __shared__ float tile[32][33];
  int kt = blockIdx.x, nt = blockIdx.y;
  int c = threadIdx.x & 31, rp = threadIdx.x >> 5;
#pragma unroll
  for (int p = 0; p < 4; ++p) { int r = p*8+rp; tile[r][c] = W[(size_t)(kt*32 + r)*1024 + nt*32 + c]; }
  __syncthreads();
#pragma unroll
  for (int p = 0; p < 4; ++p) { int r = p*8+rp; Wt[(size_t)(nt*32 + r)*1024 + kt*32 + c] = (f16)tile[c][r]; }
}

// ---------------- prep: Wspec (256,768) f32 -> WspecT (512,256) f16 ----
__global__ __launch_bounds__(256) void prep_WspecT(const float* __restrict__ W, f16* __restrict__ Wt) {
  __shared__ float tile[32][33];
  int jt = blockIdx.x, ct = blockIdx.y;
  int c = threadIdx.x & 31, rp = threadIdx.x >> 5;
#pragma unroll
  for (int p = 0; p < 4; ++p) { int r = p*8+rp; tile[r][c] = W[(size_t)(ct*32 + r)*768 + jt*32 + c]; }
  __syncthreads();
#pragma unroll
  for (int p = 0; p < 4; ++p) { int r = p*8+rp; Wt[(size_t)(jt*32 + r)*256 + ct*32 + c] = (f16)tile[c][r]; }
}

// ---------------- generic 128x128x(32*KSTEPS) f16 GEMM, LDS-staged, m97 structure ----
// SCALEQ: multiply C by SCALE when n0<256 (folds spec softmax scale into q_s, exact pow2)
template<int KSTEPS, int AST, int BST, int CST, bool SCALEQ>
__global__ __launch_bounds__(256) void gemm128(const f16* __restrict__ Ag, const f16* __restrict__ Bg,
                                               f16* __restrict__ Cg, size_t aB, size_t bB, size_t cB) {
  __shared__ f16 As[128*32];
  __shared__ f16 Bs[128*32];
  const f16* A = Ag + (size_t)blockIdx.z*aB;
  const f16* B = Bg + (size_t)blockIdx.z*bB;
  f16* C = Cg + (size_t)blockIdx.z*cB;
  int t = threadIdx.x, lane = t & 63, wave = t >> 6;
  int l15 = lane & 15, l4 = lane >> 4;
  int wm = wave & 1, wn = wave >> 1;
  size_t m0 = (size_t)blockIdx.x*128, n0 = (size_t)blockIdx.y*128;
  float cscale = (SCALEQ && n0 < 256) ? SCALE : 1.0f;
  f32x4 acc[4][4];
#pragma unroll
  for (int i=0;i<4;++i)
#pragma unroll
    for (int j=0;j<4;++j) acc[i][j] = (f32x4){0.f,0.f,0.f,0.f};
  int rowS[2], chS[2];
#pragma unroll
  for (int c=0;c<2;++c) {
    int slot = c*256 + t;
    rowS[c] = slot >> 2;
    chS[c]  = (slot & 3) ^ ((slot >> 3) & 3);
  }
  int pc = (l4 ^ ((l15 >> 1) & 3)) * 8;
  const f16* Afr = As + (wm*64 + l15)*32 + pc;
  const f16* Bfr = Bs + (wn*64 + l15)*32 + pc;
  for (int ks = 0; ks < KSTEPS; ++ks) {
    int k0 = ks*32;
#pragma unroll
    for (int c=0;c<2;++c) {
      GLL(A + (m0 + rowS[c])*(size_t)AST + k0 + chS[c]*8, &As[(c*256 + wave*64)*8]);
      GLL(B + (n0 + rowS[c])*(size_t)BST + k0 + chS[c]*8, &Bs[(c*256 + wave*64)*8]);
    }
    __syncthreads();
    half8 a[4], bb[4];
#pragma unroll
    for (int mi=0;mi<4;++mi) a[mi]  = *(const half8*)(Afr + mi*16*32);
#pragma unroll
    for (int ni=0;ni<4;++ni) bb[ni] = *(const half8*)(Bfr + ni*16*32);
#pragma unroll
    for (int mi=0;mi<4;++mi)
#pragma unroll
      for (int ni=0;ni<4;++ni)
        acc[mi][ni] = __builtin_amdgcn_mfma_f32_16x16x32_f16(a[mi], bb[ni], acc[mi][ni], 0,0,0);
    __syncthreads();
  }
#pragma unroll
  for (int mi=0;mi<4;++mi)
#pragma unroll
    for (int ni=0;ni<4;++ni)
#pragma unroll
      for (int j=0;j<4;++j) {
        size_t row = m0 + wm*64 + mi*16 + 4*l4 + j;
        size_t col = n0 + wn*64 + ni*16 + l15;
        C[row*CST + col] = (f16)(acc[mi][ni][j] * cscale);
      }
}

// ---------------- qattn: per (b,h): q = x_center @ Wq, attn over 256, out -> attnout (64,512) f32 ----
__global__ __launch_bounds__(256) void qattn(const float* __restrict__ x, const float* __restrict__ Wq,
                                             const f16* __restrict__ kv, float* __restrict__ attnout) {
  int b = blockIdx.x, h = blockIdx.y;
  int t = threadIdx.x;
  __shared__ float xc[1024];
  __shared__ float qh[64];
  __shared__ float p[256];
  __shared__ float part[4][64];
  __shared__ float redw[4];
  const float* xcg = x + ((size_t)b*256 + 128)*1024;
#pragma unroll
  for (int i = 0; i < 4; ++i) xc[t + 256*i] = xcg[t + 256*i];
  __syncthreads();
  int d = t & 63, chunk = t >> 6;
  {
    float s = 0.f;
    const float* wq = Wq + (size_t)(chunk*256)*512 + h*64 + d;
#pragma unroll 8
    for (int c = 0; c < 256; ++c) s += xc[chunk*256 + c] * wq[(size_t)c*512];
    part[chunk][d] = s;
  }
  __syncthreads();
  if (t < 64) qh[t] = part[0][t]+part[1][t]+part[2][t]+part[3][t];
  __syncthreads();
  {
    const f16* kp = kv + ((size_t)b*256 + t)*1024 + h*64;
    float acc = 0.f;
#pragma unroll
    for (int d8 = 0; d8 < 8; ++d8) {
      half8 kk = *(const half8*)(kp + d8*8);
#pragma unroll
      for (int j = 0; j < 8; ++j) acc += (float)kk[j] * qh[d8*8+j];
    }
    p[t] = acc * SCALE;
  }
  __syncthreads();
  int lane = t & 63, wid = t >> 6;
  float v = p[t];
#pragma unroll
  for (int o = 32; o >= 1; o >>= 1) v = fmaxf(v, __shfl_xor(v, o));
  if (lane == 0) redw[wid] = v;
  __syncthreads();
  float m = fmaxf(fmaxf(redw[0],redw[1]),fmaxf(redw[2],redw[3]));
  float e = __expf(p[t] - m);
  __syncthreads();
  v = e;
#pragma unroll
  for (int o = 32; o >= 1; o >>= 1) v += __shfl_xor(v, o);
  if (lane == 0) redw[wid] = v;
  __syncthreads();
  float Z = redw[0]+redw[1]+redw[2]+redw[3];
  p[t] = e / Z;
  __syncthreads();
  {
    float o = 0.f;
    const f16* vp = kv + ((size_t)b*256 + chunk*64)*1024 + 512 + h*64 + d;
#pragma unroll 8
    for (int n = 0; n < 64; ++n) o += p[chunk*64 + n] * (float)vp[(size_t)n*1024];
    part[chunk][d] = o;
  }
  __syncthreads();
  if (t < 64) attnout[(size_t)b*512 + h*64 + t] = part[0][t]+part[1][t]+part[2][t]+part[3][t];
}

// ---------------- spatial partial ----------------
__global__ __launch_bounds__(256) void spatialp(const float* __restrict__ attnout, const float* __restrict__ Wout,
                                                float* __restrict__ partial) {
  int ic = blockIdx.x, b = blockIdx.y;
  int t = threadIdx.x;
  __shared__ float ao[128];
  if (t < 128) ao[t] = attnout[(size_t)b*512 + ic*128 + t];
  __syncthreads();
  const float* W = Wout + (size_t)ic*128*1024 + t*4;
  f32x4 acc0 = (f32x4){0.f,0.f,0.f,0.f};
  f32x4 acc1 = (f32x4){0.f,0.f,0.f,0.f};
#pragma unroll 4
  for (int i = 0; i < 128; i += 2) {
    f32x4 w0 = *(const f32x4*)(W + (size_t)i*1024);
    f32x4 w1 = *(const f32x4*)(W + (size_t)(i+1)*1024);
    float a0 = ao[i], a1 = ao[i+1];
    acc0[0] += a0*w0[0]; acc0[1] += a0*w0[1]; acc0[2] += a0*w0[2]; acc0[3] += a0*w0[3];
    acc1[0] += a1*w1[0]; acc1[1] += a1*w1[1]; acc1[2] += a1*w1[2]; acc1[3] += a1*w1[3];
  }
  f32x4 acc;
#pragma unroll
  for (int j=0;j<4;++j) acc[j] = acc0[j] + acc1[j];
  *(f32x4*)(partial + ((size_t)(b*4 + ic))*1024 + t*4) = acc;
}

// ---------------- spatial reduce ----------------
__global__ __launch_bounds__(256) void spatialr(const float* __restrict__ partial, const float* __restrict__ bout,
                                                float* __restrict__ spatial) {
  int b = blockIdx.x, t = threadIdx.x;
  f32x4 s = *(const f32x4*)(bout + t*4);
#pragma unroll
  for (int ic = 0; ic < 4; ++ic) {
    f32x4 p = *(const f32x4*)(partial + ((size_t)(b*4 + ic))*1024 + t*4);
#pragma unroll
    for (int j=0;j<4;++j) s[j] += p[j];
  }
  *(f32x4*)(spatial + (size_t)b*1024 + t*4) = s;
}

// ---------------- spec v3: 512 thr / 8 waves; block = 64 i-rows x 1024 e; 2-phase dbuf ----
// wave ew owns e-cols [ew*128, ew*128+128); A tile (64x32) + B tile (1024x32) staged per k-step.
// grid 1024, XCD-aware decode: all 16 i-blocks of a batch land on one XCD (k_s L2 reuse).
__global__ __launch_bounds__(512) void speck(const f16* __restrict__ qks, const float* __restrict__ spatial,
                                             float* __restrict__ r) {
  __shared__ f16 Bs[2][1024*32];                       // 2 x 64KB
  __shared__ f16 As[2][64*32];                         // 2 x 4KB
  __shared__ __attribute__((aligned(16))) float sm[64*8];
  __shared__ __attribute__((aligned(16))) float sz[64*8];
  int bid = blockIdx.x;
  int xcd = bid & 7, q = bid >> 3;
  int b = xcd*8 + (q >> 4);
  int iblk = q & 15;
  int t = threadIdx.x, lane = t & 63, wave = t >> 6;
  int l15 = lane & 15, l4 = lane >> 4;
  int ew = wave;
  const f16* qs = qks + (size_t)b*1024*512;
  int i0 = iblk*64;

  f32x4 acc[4][8];
#pragma unroll
  for (int rt=0;rt<4;++rt)
#pragma unroll
    for (int ct=0;ct<8;++ct) acc[rt][ct] = (f32x4){0.f,0.f,0.f,0.f};
  int pc = (l4 ^ ((l15 >> 1) & 3)) * 8;

  auto STAGE = [&](int buf, int ks) {
    int k0 = ks*32;
#pragma unroll
    for (int c = 0; c < 8; ++c) {
      int slot = c*512 + t;
      int row = slot >> 2;
      int ch = (slot & 3) ^ ((slot >> 3) & 3);
      GLL(qs + 256 + (size_t)row*512 + k0 + ch*8, &Bs[buf][(c*512 + wave*64)*8]);
    }
    if (wave < 4) {
      int slot = wave*64 + lane;
      int row = slot >> 2;
      int ch = (slot & 3) ^ ((slot >> 3) & 3);
      GLL(qs + (size_t)(i0 + row)*512 + k0 + ch*8, &As[buf][(wave*64)*8]);
    }
  };

  STAGE(0, 0);
  asm volatile("s_waitcnt vmcnt(0)" ::: "memory");
  __syncthreads();
  for (int ks = 0; ks < 8; ++ks) {
    int cur = ks & 1;
    if (ks < 7) STAGE(cur ^ 1, ks + 1);
    half8 a[4];
#pragma unroll
    for (int rt = 0; rt < 4; ++rt) a[rt] = *(const half8*)(&As[cur][(rt*16 + l15)*32 + pc]);
#pragma unroll
    for (int ct = 0; ct < 8; ++ct) {
      half8 bb = *(const half8*)(&Bs[cur][(ew*128 + ct*16 + l15)*32 + pc]);
#pragma unroll
      for (int rt = 0; rt < 4; ++rt)
        acc[rt][ct] = __builtin_amdgcn_mfma_f32_16x16x32_f16(a[rt], bb, acc[rt][ct], 0,0,0);
    }
    asm volatile("s_waitcnt vmcnt(0)" ::: "memory");
    __syncthreads();
  }
  // ---- softmax over full rows (split across 8 waves, combine via LDS) ----
  // lane holds rows row = rt*16 + 4*l4 + jj (16 of them), cols ew*128 + ct*16 + l15
  float mr[4][4];
#pragma unroll
  for (int rt=0;rt<4;++rt)
#pragma unroll
    for (int jj=0;jj<4;++jj) {
      float mm = acc[rt][0][jj];
#pragma unroll
      for (int ct=1;ct<8;++ct) mm = fmaxf(mm, acc[rt][ct][jj]);
#pragma unroll
      for (int o=1;o<16;o<<=1) mm = fmaxf(mm, __shfl_xor(mm, o));
      mr[rt][jj] = mm;
    }
  if (l15 == 0) {
#pragma unroll
    for (int rt=0;rt<4;++rt)
#pragma unroll
      for (int jj=0;jj<4;++jj) sm[(rt*16 + 4*l4 + jj)*8 + wave] = mr[rt][jj];
  }
  __syncthreads();
#pragma unroll
  for (int rt=0;rt<4;++rt)
#pragma unroll
    for (int jj=0;jj<4;++jj) {
      int row = rt*16 + 4*l4 + jj;
      f32x4 lo = *(const f32x4*)(&sm[row*8]);
      f32x4 hi = *(const f32x4*)(&sm[row*8+4]);
      mr[rt][jj] = fmaxf(fmaxf(fmaxf(lo[0],lo[1]),fmaxf(lo[2],lo[3])),
                         fmaxf(fmaxf(hi[0],hi[1]),fmaxf(hi[2],hi[3])));
    }
  float zr[4][4];
#pragma unroll
  for (int rt=0;rt<4;++rt)
#pragma unroll
    for (int jj=0;jj<4;++jj) {
      float zz = 0.f;
#pragma unroll
      for (int ct=0;ct<8;++ct) {
        float e = __expf(acc[rt][ct][jj] - mr[rt][jj]);
        acc[rt][ct][jj] = e;
        zz += e;
      }
#pragma unroll
      for (int o=1;o<16;o<<=1) zz += __shfl_xor(zz, o);
      zr[rt][jj] = zz;
    }
  if (l15 == 0) {
#pragma unroll
    for (int rt=0;rt<4;++rt)
#pragma unroll
      for (int jj=0;jj<4;++jj) sz[(rt*16 + 4*l4 + jj)*8 + wave] = zr[rt][jj];
  }
  __syncthreads();
  float f[4][4];
#pragma unroll
  for (int rt=0;rt<4;++rt)
#pragma unroll
    for (int jj=0;jj<4;++jj) {
      int row = rt*16 + 4*l4 + jj;
      f32x4 lo = *(const f32x4*)(&sz[row*8]);
      f32x4 hi = *(const f32x4*)(&sz[row*8+4]);
      float zz = (lo[0]+lo[1]+lo[2]+lo[3]) + (hi[0]+hi[1]+hi[2]+hi[3]);
      f[rt][jj] = spatial[(size_t)b*1024 + i0 + row] / zz;
    }
  float* rb = r + (size_t)b*1024;
#pragma unroll
  for (int ct=0;ct<8;++ct) {
    float v = 0.f;
#pragma unroll
    for (int rt=0;rt<4;++rt)
#pragma unroll
      for (int jj=0;jj<4;++jj) v += f[rt][jj]*acc[rt][ct][jj];
    v += __shfl_xor(v, 16);
    v += __shfl_xor(v, 32);
    if (l4 == 0) atomicAdd(rb + ew*128 + ct*16 + l15, v);
  }
}

// ---------------- broadcast: out[b,n,:] = r[b,:] ----------------
__global__ __launch_bounds__(256) void bcast(const float* __restrict__ r, float* __restrict__ out) {
  size_t row = blockIdx.x;
  int b = (int)(row >> 8);
  f32x4 v = *(const f32x4*)(r + (size_t)b*1024 + threadIdx.x*4);
  *(f32x4*)(out + row*1024 + (size_t)threadIdx.x*4) = v;
}

extern "C" void kernel_launch(void* const* d_in, const int* in_sizes, int n_in,
                              void* d_out, int out_size, void* d_ws, size_t ws_size,
                              hipStream_t stream) {
  const float* x     = (const float*)d_in[0];
  const float* Wq    = (const float*)d_in[1];
  const float* Wkv   = (const float*)d_in[2];
  const float* Wout  = (const float*)d_in[3];
  const float* bout  = (const float*)d_in[4];
  const float* Wspec = (const float*)d_in[5];
  float* out = (float*)d_out;
  char* ws = (char*)d_ws;
  f16*  qks     = (f16*)(ws);
  f16*  kv      = (f16*)(ws);
  float* partial = (float*)(ws);
  f16*  x16     = (f16*)(ws + 33554432);
  f16*  xT      = (f16*)(ws + 67108864);         // 32 MB
  f16*  WkvT    = (f16*)(ws + 100663296);        // 2 MB
  f16*  WspecT  = (f16*)(ws + 102760448);        // 256 KB
  float* attnout = (float*)(ws + 103022592);     // 128 KB
  float* spatial = (float*)(ws + 103153664);     // 256 KB
  float* rvec    = (float*)(ws + 103415808);     // 256 KB
  (void)in_sizes; (void)n_in; (void)out_size; (void)ws_size;

  prep_x16   <<<dim3(8192),      dim3(256), 0, stream>>>(x, x16);
  prep_xT    <<<dim3(32, 8, 64), dim3(256), 0, stream>>>(x16, xT);
  prep_WkvT  <<<dim3(32, 32),    dim3(256), 0, stream>>>(Wkv, WkvT);
  prep_WspecT<<<dim3(16, 8),     dim3(256), 0, stream>>>(Wspec, WspecT);
  gemm128<32,1024,1024,1024,false><<<dim3(128, 8, 1), dim3(256), 0, stream>>>(x16, WkvT, kv, 0, 0, 0);
  qattn      <<<dim3(64, 8),     dim3(256), 0, stream>>>(x, Wq, kv, attnout);
  spatialp   <<<dim3(4, 64),     dim3(256), 0, stream>>>(attnout, Wout, partial);
  spatialr   <<<dim3(64),        dim3(256), 0, stream>>>(partial, bout, spatial);
  gemm128<8,256,256,512,true><<<dim3(8, 4, 64), dim3(256), 0, stream>>>(xT, WspecT, qks,
                                                                   (size_t)1024*256, 0, (size_t)1024*512);
  hipMemsetAsync(rvec, 0, 64*1024*sizeof(float), stream);
  speck      <<<dim3(1024),      dim3(512), 0, stream>>>(qks, spatial, rvec);
  bcast      <<<dim3(16384),     dim3(256), 0, stream>>>(rvec, out);
}

// Round 5
// 236.770 us; speedup vs baseline: 3.9103x; 1.0745x over previous
//
#include <hip/hip_runtime.h>
#include <hip/hip_bf16.h>
#include <cstdint>

typedef _Float16 f16;
typedef _Float16 half8 __attribute__((ext_vector_type(8)));
typedef float f32x4 __attribute__((ext_vector_type(4)));

#define SCALE 0.125f

// async global->LDS, 16B per lane, dest = wave-uniform base + lane*16
#define GLL(src, dst) __builtin_amdgcn_global_load_lds( \
    (const __attribute__((address_space(1))) unsigned int*)(src), \
    (__attribute__((address_space(3))) unsigned int*)(dst), 16, 0, 0)

// ---------------- fused prep: x f32 -> x16 (row-major f16) + xT (64,1024,256) f16 ----------------
__global__ __launch_bounds__(256) void prep_xf(const float* __restrict__ x, f16* __restrict__ x16,
                                               f16* __restrict__ xT) {
  __shared__ f16 tile[32][33];
  int b = blockIdx.z, nt = blockIdx.y, dt = blockIdx.x;
  int c = threadIdx.x & 31, rp = threadIdx.x >> 5;
  const float* xb = x + ((size_t)b*256 + nt*32)*1024 + dt*32;
  f16* x16b = x16 + ((size_t)b*256 + nt*32)*1024 + dt*32;
#pragma unroll
  for (int p = 0; p < 4; ++p) {
    int r = p*8 + rp;
    f16 h = (f16)xb[(size_t)r*1024 + c];
    x16b[(size_t)r*1024 + c] = h;
    tile[r][c] = h;
  }
  __syncthreads();
  f16* o = xT + ((size_t)b*1024 + dt*32)*256 + nt*32;
#pragma unroll
  for (int p = 0; p < 4; ++p) { int r = p*8 + rp; o[(size_t)r*256 + c] = tile[c][r]; }
}

// ---------------- prep: Wkv (1024,1024) f32 -> WkvT f16 ----
__global__ __launch_bounds__(256) void prep_WkvT(const float* __restrict__ W, f16* __restrict__ Wt) {
  __shared__ float tile[32][33];
  int kt = blockIdx.x, nt = blockIdx.y;
  int c = threadIdx.x & 31, rp = threadIdx.x >> 5;
#pragma unroll
  for (int p = 0; p < 4; ++p) { int r = p*8+rp; tile[r][c] = W[(size_t)(kt*32 + r)*1024 + nt*32 + c]; }
  __syncthreads();
#pragma unroll
  for (int p = 0; p < 4; ++p) { int r = p*8+rp; Wt[(size_t)(nt*32 + r)*1024 + kt*32 + c] = (f16)tile[c][r]; }
}

// ---------------- prep: Wspec (256,768) f32 -> WspecT (512,256) f16 ----
__global__ __launch_bounds__(256) void prep_WspecT(const float* __restrict__ W, f16* __restrict__ Wt) {
  __shared__ float tile[32][33];
  int jt = blockIdx.x, ct = blockIdx.y;
  int c = threadIdx.x & 31, rp = threadIdx.x >> 5;
#pragma unroll
  for (int p = 0; p < 4; ++p) { int r = p*8+rp; tile[r][c] = W[(size_t)(ct*32 + r)*768 + jt*32 + c]; }
  __syncthreads();
#pragma unroll
  for (int p = 0; p < 4; ++p) { int r = p*8+rp; Wt[(size_t)(jt*32 + r)*256 + ct*32 + c] = (f16)tile[c][r]; }
}

// ---------------- 128x128x(32*KSTEPS) f16 GEMM, double-buffered + counted vmcnt (T3/T4) ----
template<int KSTEPS, int AST, int BST, int CST, bool SCALEQ>
__global__ __launch_bounds__(256) void gemm128(const f16* __restrict__ Ag, const f16* __restrict__ Bg,
                                               f16* __restrict__ Cg, size_t aB, size_t bB, size_t cB) {
  __shared__ f16 As[2][128*32];
  __shared__ f16 Bs[2][128*32];
  const f16* A = Ag + (size_t)blockIdx.z*aB;
  const f16* B = Bg + (size_t)blockIdx.z*bB;
  f16* C = Cg + (size_t)blockIdx.z*cB;
  int t = threadIdx.x, lane = t & 63, wave = t >> 6;
  int l15 = lane & 15, l4 = lane >> 4;
  int wm = wave & 1, wn = wave >> 1;
  size_t m0 = (size_t)blockIdx.x*128, n0 = (size_t)blockIdx.y*128;
  float cscale = (SCALEQ && n0 < 256) ? SCALE : 1.0f;
  f32x4 acc[4][4];
#pragma unroll
  for (int i=0;i<4;++i)
#pragma unroll
    for (int j=0;j<4;++j) acc[i][j] = (f32x4){0.f,0.f,0.f,0.f};
  int rowS[2], chS[2];
#pragma unroll
  for (int c=0;c<2;++c) {
    int slot = c*256 + t;
    rowS[c] = slot >> 2;
    chS[c]  = (slot & 3) ^ ((slot >> 3) & 3);
  }
  int pc = (l4 ^ ((l15 >> 1) & 3)) * 8;

  auto STAGE = [&](int buf, int ks) {   // 4 GLL per thread -> uniform 4/wave
    int k0 = ks*32;
#pragma unroll
    for (int c=0;c<2;++c) {
      GLL(A + (m0 + rowS[c])*(size_t)AST + k0 + chS[c]*8, &As[buf][(c*256 + wave*64)*8]);
      GLL(B + (n0 + rowS[c])*(size_t)BST + k0 + chS[c]*8, &Bs[buf][(c*256 + wave*64)*8]);
    }
  };

  STAGE(0, 0);
#pragma unroll 2
  for (int ks = 0; ks < KSTEPS; ++ks) {
    int cur = ks & 1;
    if (ks + 1 < KSTEPS) {
      STAGE(cur ^ 1, ks + 1);
      asm volatile("s_waitcnt vmcnt(4)" ::: "memory");   // prior tile landed; next 4 in flight
    } else {
      asm volatile("s_waitcnt vmcnt(0)" ::: "memory");
    }
    __builtin_amdgcn_s_barrier();
    __builtin_amdgcn_sched_barrier(0);
    half8 a[4], bb[4];
    const f16* Af = &As[cur][(wm*64 + l15)*32 + pc];
    const f16* Bf = &Bs[cur][(wn*64 + l15)*32 + pc];
#pragma unroll
    for (int mi=0;mi<4;++mi) a[mi]  = *(const half8*)(Af + mi*16*32);
#pragma unroll
    for (int ni=0;ni<4;++ni) bb[ni] = *(const half8*)(Bf + ni*16*32);
    __builtin_amdgcn_s_setprio(1);
#pragma unroll
    for (int mi=0;mi<4;++mi)
#pragma unroll
      for (int ni=0;ni<4;++ni)
        acc[mi][ni] = __builtin_amdgcn_mfma_f32_16x16x32_f16(a[mi], bb[ni], acc[mi][ni], 0,0,0);
    __builtin_amdgcn_s_setprio(0);
    __builtin_amdgcn_sched_barrier(0);
    __builtin_amdgcn_s_barrier();   // licenses next iteration's STAGE overwrite
  }
#pragma unroll
  for (int mi=0;mi<4;++mi)
#pragma unroll
    for (int ni=0;ni<4;++ni)
#pragma unroll
      for (int j=0;j<4;++j) {
        size_t row = m0 + wm*64 + mi*16 + 4*l4 + j;
        size_t col = n0 + wn*64 + ni*16 + l15;
        C[row*CST + col] = (f16)(acc[mi][ni][j] * cscale);
      }
}

// ---------------- qattn: per (b,h): q = x_center @ Wq, attn over 256, out -> attnout (64,512) f32 ----
__global__ __launch_bounds__(256) void qattn(const float* __restrict__ x, const float* __restrict__ Wq,
                                             const f16* __restrict__ kv, float* __restrict__ attnout) {
  int b = blockIdx.x, h = blockIdx.y;
  int t = threadIdx.x;
  __shared__ float xc[1024];
  __shared__ float qh[64];
  __shared__ float p[256];
  __shared__ float part[4][64];
  __shared__ float redw[4];
  const float* xcg = x + ((size_t)b*256 + 128)*1024;
#pragma unroll
  for (int i = 0; i < 4; ++i) xc[t + 256*i] = xcg[t + 256*i];
  __syncthreads();
  int d = t & 63, chunk = t >> 6;
  {
    float s = 0.f;
    const float* wq = Wq + (size_t)(chunk*256)*512 + h*64 + d;
#pragma unroll 8
    for (int c = 0; c < 256; ++c) s += xc[chunk*256 + c] * wq[(size_t)c*512];
    part[chunk][d] = s;
  }
  __syncthreads();
  if (t < 64) qh[t] = part[0][t]+part[1][t]+part[2][t]+part[3][t];
  __syncthreads();
  {
    const f16* kp = kv + ((size_t)b*256 + t)*1024 + h*64;
    float acc = 0.f;
#pragma unroll
    for (int d8 = 0; d8 < 8; ++d8) {
      half8 kk = *(const half8*)(kp + d8*8);
#pragma unroll
      for (int j = 0; j < 8; ++j) acc += (float)kk[j] * qh[d8*8+j];
    }
    p[t] = acc * SCALE;
  }
  __syncthreads();
  int lane = t & 63, wid = t >> 6;
  float v = p[t];
#pragma unroll
  for (int o = 32; o >= 1; o >>= 1) v = fmaxf(v, __shfl_xor(v, o));
  if (lane == 0) redw[wid] = v;
  __syncthreads();
  float m = fmaxf(fmaxf(redw[0],redw[1]),fmaxf(redw[2],redw[3]));
  float e = __expf(p[t] - m);
  __syncthreads();
  v = e;
#pragma unroll
  for (int o = 32; o >= 1; o >>= 1) v += __shfl_xor(v, o);
  if (lane == 0) redw[wid] = v;
  __syncthreads();
  float Z = redw[0]+redw[1]+redw[2]+redw[3];
  p[t] = e / Z;
  __syncthreads();
  {
    float o = 0.f;
    const f16* vp = kv + ((size_t)b*256 + chunk*64)*1024 + 512 + h*64 + d;
#pragma unroll 8
    for (int n = 0; n < 64; ++n) o += p[chunk*64 + n] * (float)vp[(size_t)n*1024];
    part[chunk][d] = o;
  }
  __syncthreads();
  if (t < 64) attnout[(size_t)b*512 + h*64 + t] = part[0][t]+part[1][t]+part[2][t]+part[3][t];
}

// ---------------- spatial partial ----------------
__global__ __launch_bounds__(256) void spatialp(const float* __restrict__ attnout, const float* __restrict__ Wout,
                                                float* __restrict__ partial) {
  int ic = blockIdx.x, b = blockIdx.y;
  int t = threadIdx.x;
  __shared__ float ao[128];
  if (t < 128) ao[t] = attnout[(size_t)b*512 + ic*128 + t];
  __syncthreads();
  const float* W = Wout + (size_t)ic*128*1024 + t*4;
  f32x4 acc0 = (f32x4){0.f,0.f,0.f,0.f};
  f32x4 acc1 = (f32x4){0.f,0.f,0.f,0.f};
#pragma unroll 4
  for (int i = 0; i < 128; i += 2) {
    f32x4 w0 = *(const f32x4*)(W + (size_t)i*1024);
    f32x4 w1 = *(const f32x4*)(W + (size_t)(i+1)*1024);
    float a0 = ao[i], a1 = ao[i+1];
    acc0[0] += a0*w0[0]; acc0[1] += a0*w0[1]; acc0[2] += a0*w0[2]; acc0[3] += a0*w0[3];
    acc1[0] += a1*w1[0]; acc1[1] += a1*w1[1]; acc1[2] += a1*w1[2]; acc1[3] += a1*w1[3];
  }
  f32x4 acc;
#pragma unroll
  for (int j=0;j<4;++j) acc[j] = acc0[j] + acc1[j];
  *(f32x4*)(partial + ((size_t)(b*4 + ic))*1024 + t*4) = acc;
}

// ---------------- spatial reduce ----------------
__global__ __launch_bounds__(256) void spatialr(const float* __restrict__ partial, const float* __restrict__ bout,
                                                float* __restrict__ spatial) {
  int b = blockIdx.x, t = threadIdx.x;
  f32x4 s = *(const f32x4*)(bout + t*4);
#pragma unroll
  for (int ic = 0; ic < 4; ++ic) {
    f32x4 p = *(const f32x4*)(partial + ((size_t)(b*4 + ic))*1024 + t*4);
#pragma unroll
    for (int j=0;j<4;++j) s[j] += p[j];
  }
  *(f32x4*)(spatial + (size_t)b*1024 + t*4) = s;
}

// ---------------- spec v4: 64i x 1024e per block; dbuf + counted vmcnt(9); no-max softmax ----
// SCALE is pre-folded into q_s. exp(L) is safe in f32: L <= ~46 worst-case (diagonal chi^2 row).
__global__ __launch_bounds__(512) void speck(const f16* __restrict__ qks, const float* __restrict__ spatial,
                                             float* __restrict__ r) {
  __shared__ f16 Bs[2][1024*32];                       // 2 x 64KB
  __shared__ f16 As[2][64*32];                         // 2 x 4KB
  __shared__ __attribute__((aligned(16))) float sz[64*8];
  int bid = blockIdx.x;
  int xcd = bid & 7, q = bid >> 3;
  int b = xcd*8 + (q >> 4);                            // batch pinned to one XCD
  int iblk = q & 15;
  int t = threadIdx.x, lane = t & 63, wave = t >> 6;
  int l15 = lane & 15, l4 = lane >> 4;
  int ew = wave;
  const f16* qs = qks + (size_t)b*1024*512;
  int i0 = iblk*64;

  f32x4 acc[4][8];
#pragma unroll
  for (int rt=0;rt<4;++rt)
#pragma unroll
    for (int ct=0;ct<8;++ct) acc[rt][ct] = (f32x4){0.f,0.f,0.f,0.f};
  int pc = (l4 ^ ((l15 >> 1) & 3)) * 8;

  auto STAGE = [&](int buf, int ks) {   // uniform 9 GLL per wave (A staged twice: waves w and w^4)
    int k0 = ks*32;
#pragma unroll
    for (int c = 0; c < 8; ++c) {
      int slot = c*512 + t;
      int row = slot >> 2;
      int ch = (slot & 3) ^ ((slot >> 3) & 3);
      GLL(qs + 256 + (size_t)row*512 + k0 + ch*8, &Bs[buf][(c*512 + wave*64)*8]);
    }
    {
      int w3 = wave & 3;
      int slot = w3*64 + lane;
      int row = slot >> 2;
      int ch = (slot & 3) ^ ((slot >> 3) & 3);
      GLL(qs + (size_t)(i0 + row)*512 + k0 + ch*8, &As[buf][(w3*64)*8]);
    }
  };

  STAGE(0, 0);
  for (int ks = 0; ks < 8; ++ks) {
    int cur = ks & 1;
    if (ks < 7) {
      STAGE(cur ^ 1, ks + 1);
      asm volatile("s_waitcnt vmcnt(9)" ::: "memory");   // prior tile's 9 landed; next 9 in flight
    } else {
      asm volatile("s_waitcnt vmcnt(0)" ::: "memory");
    }
    __builtin_amdgcn_s_barrier();
    __builtin_amdgcn_sched_barrier(0);
    half8 a[4];
#pragma unroll
    for (int rt = 0; rt < 4; ++rt) a[rt] = *(const half8*)(&As[cur][(rt*16 + l15)*32 + pc]);
    __builtin_amdgcn_s_setprio(1);
#pragma unroll
    for (int ct = 0; ct < 8; ++ct) {
      half8 bb = *(const half8*)(&Bs[cur][(ew*128 + ct*16 + l15)*32 + pc]);
#pragma unroll
      for (int rt = 0; rt < 4; ++rt)
        acc[rt][ct] = __builtin_amdgcn_mfma_f32_16x16x32_f16(a[rt], bb, acc[rt][ct], 0,0,0);
    }
    __builtin_amdgcn_s_setprio(0);
    __builtin_amdgcn_sched_barrier(0);
    __builtin_amdgcn_s_barrier();
  }
  // ---- no-max softmax: exp directly (f32-safe), row sums combined across 8 waves ----
  float zr[4][4];
#pragma unroll
  for (int rt=0;rt<4;++rt)
#pragma unroll
    for (int jj=0;jj<4;++jj) {
      float zz = 0.f;
#pragma unroll
      for (int ct=0;ct<8;++ct) {
        float e = __expf(acc[rt][ct][jj]);
        acc[rt][ct][jj] = e;
        zz += e;
      }
#pragma unroll
      for (int o=1;o<16;o<<=1) zz += __shfl_xor(zz, o);
      zr[rt][jj] = zz;
    }
  if (l15 == 0) {
#pragma unroll
    for (int rt=0;rt<4;++rt)
#pragma unroll
      for (int jj=0;jj<4;++jj) sz[(rt*16 + 4*l4 + jj)*8 + wave] = zr[rt][jj];
  }
  __syncthreads();
  float f[4][4];
#pragma unroll
  for (int rt=0;rt<4;++rt)
#pragma unroll
    for (int jj=0;jj<4;++jj) {
      int row = rt*16 + 4*l4 + jj;
      f32x4 lo = *(const f32x4*)(&sz[row*8]);
      f32x4 hi = *(const f32x4*)(&sz[row*8+4]);
      float zz = (lo[0]+lo[1]+lo[2]+lo[3]) + (hi[0]+hi[1]+hi[2]+hi[3]);
      f[rt][jj] = spatial[(size_t)b*1024 + i0 + row] / zz;
    }
  float* rb = r + (size_t)b*1024;
#pragma unroll
  for (int ct=0;ct<8;++ct) {
    float v = 0.f;
#pragma unroll
    for (int rt=0;rt<4;++rt)
#pragma unroll
      for (int jj=0;jj<4;++jj) v += f[rt][jj]*acc[rt][ct][jj];
    v += __shfl_xor(v, 16);
    v += __shfl_xor(v, 32);
    if (l4 == 0) atomicAdd(rb + ew*128 + ct*16 + l15, v);
  }
}

// ---------------- broadcast: out[b,n,:] = r[b,:] ----------------
__global__ __launch_bounds__(256) void bcast(const float* __restrict__ r, float* __restrict__ out) {
  size_t row = blockIdx.x;
  int b = (int)(row >> 8);
  f32x4 v = *(const f32x4*)(r + (size_t)b*1024 + threadIdx.x*4);
  *(f32x4*)(out + row*1024 + (size_t)threadIdx.x*4) = v;
}

extern "C" void kernel_launch(void* const* d_in, const int* in_sizes, int n_in,
                              void* d_out, int out_size, void* d_ws, size_t ws_size,
                              hipStream_t stream) {
  const float* x     = (const float*)d_in[0];
  const float* Wq    = (const float*)d_in[1];
  const float* Wkv   = (const float*)d_in[2];
  const float* Wout  = (const float*)d_in[3];
  const float* bout  = (const float*)d_in[4];
  const float* Wspec = (const float*)d_in[5];
  float* out = (float*)d_out;
  char* ws = (char*)d_ws;
  // workspace aliases (stream-ordered):
  //   qks @0 64MB (gemm_qs -> speck); kv @0 32MB alias (dead before gemm_qs);
  //   partial @0 1MB alias (between qattn and gemm_qs); x16 @32M alias (dead after gemm_kv)
  f16*  qks     = (f16*)(ws);
  f16*  kv      = (f16*)(ws);
  float* partial = (float*)(ws);
  f16*  x16     = (f16*)(ws + 33554432);
  f16*  xT      = (f16*)(ws + 67108864);         // 32 MB
  f16*  WkvT    = (f16*)(ws + 100663296);        // 2 MB
  f16*  WspecT  = (f16*)(ws + 102760448);        // 256 KB
  float* attnout = (float*)(ws + 103022592);     // 128 KB
  float* spatial = (float*)(ws + 103153664);     // 256 KB
  float* rvec    = (float*)(ws + 103415808);     // 256 KB
  (void)in_sizes; (void)n_in; (void)out_size; (void)ws_size;

  prep_xf    <<<dim3(32, 8, 64), dim3(256), 0, stream>>>(x, x16, xT);
  prep_WkvT  <<<dim3(32, 32),    dim3(256), 0, stream>>>(Wkv, WkvT);
  prep_WspecT<<<dim3(16, 8),     dim3(256), 0, stream>>>(Wspec, WspecT);
  gemm128<32,1024,1024,1024,false><<<dim3(128, 8, 1), dim3(256), 0, stream>>>(x16, WkvT, kv, 0, 0, 0);
  qattn      <<<dim3(64, 8),     dim3(256), 0, stream>>>(x, Wq, kv, attnout);
  spatialp   <<<dim3(4, 64),     dim3(256), 0, stream>>>(attnout, Wout, partial);
  spatialr   <<<dim3(64),        dim3(256), 0, stream>>>(partial, bout, spatial);
  gemm128<8,256,256,512,true><<<dim3(8, 4, 64), dim3(256), 0, stream>>>(xT, WspecT, qks,
                                                                   (size_t)1024*256, 0, (size_t)1024*512);
  hipMemsetAsync(rvec, 0, 64*1024*sizeof(float), stream);
  speck      <<<dim3(1024),      dim3(512), 0, stream>>>(qks, spatial, rvec);
  bcast      <<<dim3(16384),     dim3(256), 0, stream>>>(rvec, out);
}